// Round 7
// baseline (209.007 us; speedup 1.0000x reference)
//
#include <hip/hip_runtime.h>
#include <math.h>

#define SEQ 50
#define UNITD 46
#define NEGBIG 1000000000000.0f

typedef _Float16 f16;
typedef f16 f16x4 __attribute__((ext_vector_type(4)));
typedef f16 f16x8 __attribute__((ext_vector_type(8)));
typedef float f32x4 __attribute__((ext_vector_type(4)));
typedef unsigned u32x4 __attribute__((ext_vector_type(4)));

__device__ __forceinline__ float rcpf(float x) { return __builtin_amdgcn_rcpf(x); }

// ---- per-wave arena (bytes), row stride 104 (26 words; gcd(26,32)=2 -> bank-uniform) ----
// [0,5200)      P tile [50][104B]; Q/K overlay it early; out tile reuses it later
// [5200,9984)   V^T [46][104B] (row=u, col=seq; seq 50,51 explicit zeros)
// [9984,10240)  M [64] f32 (mask, zero-padded)
#define ARENA 10240
#define QOFF 0
#define KOFF 2560
#define VOFF 5200
#define MOFF 9984
#define PSTR 104

// ---------- prologue: build f16 weight fragments in ws ----------
// ws layout (f16x8 units): [0,512)  Wi frags, idx = (nt*2+kt)*64 + lane
//                          [512,896) Wo frags, idx = 512 + (mo*2+kt)*64 + lane
__global__ void prep_kernel(const float* __restrict__ Wi,
                            const float* __restrict__ Wo,
                            f16x8* __restrict__ ws)
{
    const int lane = threadIdx.x & 63;
    const int g = lane >> 4, t = lane & 15;
    #pragma unroll
    for (int nt = 0; nt < 4; ++nt) {
        int c = t + 16 * nt; bool cok = c < 62;
        const float* wr = Wi + (size_t)(UNITD + (cok ? c : 0)) * UNITD;
        #pragma unroll
        for (int kt = 0; kt < 2; ++kt) {
            f16x8 f;
            #pragma unroll
            for (int jj = 0; jj < 8; ++jj) {
                int u = 32 * kt + 8 * g + jj;
                f[jj] = (f16)((cok && u < UNITD) ? wr[u] : 0.f);
            }
            ws[(nt * 2 + kt) * 64 + lane] = f;
        }
    }
    #pragma unroll
    for (int mo = 0; mo < 3; ++mo) {
        int o = 16 * mo + t; bool ook = o < UNITD;
        const float* wr = Wo + (size_t)(ook ? o : 0) * UNITD;
        #pragma unroll
        for (int kt = 0; kt < 2; ++kt) {
            f16x8 f;
            #pragma unroll
            for (int jj = 0; jj < 8; ++jj) {
                int u = 32 * kt + 8 * g + jj;
                f[jj] = (f16)((ook && u < UNITD) ? wr[u] : 0.f);
            }
            ws[512 + (mo * 2 + kt) * 64 + lane] = f;
        }
    }
}

__global__ __launch_bounds__(256, 4) void gau_kernel(
    const float* __restrict__ x,
    const float* __restrict__ mask,
    const f16x8* __restrict__ wf,      // precomputed fragments
    const float* __restrict__ bi,
    const float* __restrict__ bo,
    const float* __restrict__ sq,
    const float* __restrict__ oq,
    const float* __restrict__ sk,
    const float* __restrict__ ok,
    const float* __restrict__ Wq,
    const float* __restrict__ bq,
    float* __restrict__ out,
    int Btot)
{
    const int lane = threadIdx.x & 63;
    const int wid  = threadIdx.x >> 6;
    const int b    = blockIdx.x * 4 + wid;
    const int g    = lane >> 4;
    const int t    = lane & 15;

    __shared__ __align__(16) char smem[4 * ARENA];
    char* wa = smem + wid * ARENA;
    float* M = (float*)(wa + MOFF);

    if (b >= Btot) return;

    M[lane] = (lane < SEQ) ? mask[(size_t)b * SEQ + lane] : 0.f;

    // ================= phase B: h = silu(x @ Wi[46:108]^T + bi) =================
    f16x8 bfW[4][2];
    float biv[4];
    #pragma unroll
    for (int nt = 0; nt < 4; ++nt) {
        int c = t + 16 * nt;
        biv[nt] = (c < 62) ? bi[UNITD + c] : 0.f;
        #pragma unroll
        for (int kt = 0; kt < 2; ++kt)
            bfW[nt][kt] = wf[(nt * 2 + kt) * 64 + lane];
    }

    f32x4 hB[4][4];
    #pragma unroll
    for (int mt = 0; mt < 4; ++mt)
        #pragma unroll
        for (int nt = 0; nt < 4; ++nt) {
            f32x4 c; c[0] = biv[nt]; c[1] = biv[nt]; c[2] = biv[nt]; c[3] = biv[nt];
            hB[mt][nt] = c;
        }

    const float* xb = x + (size_t)b * (SEQ * UNITD);
    #pragma unroll
    for (int mt = 0; mt < 4; ++mt) {
        int row = 16 * mt + t; if (row > SEQ - 1) row = SEQ - 1;   // clamp pad rows
        const float* xr = xb + row * UNITD;
        #pragma unroll
        for (int kt = 0; kt < 2; ++kt) {
            f16x8 ax;
            #pragma unroll
            for (int jj = 0; jj < 8; jj += 2) {
                int u = 32 * kt + 8 * g + jj;
                float lo = 0.f, hi = 0.f;
                if (u < UNITD) { float2 w = *(const float2*)(xr + u); lo = w.x; hi = w.y; }
                ax[jj] = (f16)lo; ax[jj + 1] = (f16)hi;
            }
            #pragma unroll
            for (int nt = 0; nt < 4; ++nt)
                hB[mt][nt] = __builtin_amdgcn_mfma_f32_16x16x32_f16(ax, bfW[nt][kt], hB[mt][nt], 0, 0, 0);
        }
    }

    // ---- silu; v -> V^T LDS (f16, zero for seq>=50); qk channels kept in regs ----
    float qkv[4][4];
    #pragma unroll
    for (int mt = 0; mt < 4; ++mt) {
        float s2[4], s3[4];
        #pragma unroll
        for (int nt = 0; nt < 4; ++nt) {
            float sl[4];
            #pragma unroll
            for (int r = 0; r < 4; ++r) {
                float h = hB[mt][nt][r];
                sl[r] = h * rcpf(1.f + __expf(-h));
            }
            int ucol = t + 16 * nt;
            if (nt < 3 && ucol < UNITD && (mt < 3 || g == 0)) {
                int seqb = 16 * mt + 4 * g;
                f16x4 pv;
                #pragma unroll
                for (int r = 0; r < 4; ++r)
                    pv[r] = (seqb + r < SEQ) ? (f16)sl[r] : (f16)0.f;
                *(f16x4*)(wa + VOFF + ucol * PSTR + seqb * 2) = pv;
            }
            if (nt == 2) { s2[0]=sl[0]; s2[1]=sl[1]; s2[2]=sl[2]; s2[3]=sl[3]; }
            if (nt == 3) { s3[0]=sl[0]; s3[1]=sl[1]; s3[2]=sl[2]; s3[3]=sl[3]; }
        }
        #pragma unroll
        for (int r = 0; r < 4; ++r) qkv[mt][r] = (t >= 14) ? s2[r] : s3[r];
    }

    // ================= phase C: RoPE; q,k -> LDS (overlaying P region) =================
    {
        f16* Q = (f16*)(wa + QOFF);
        f16* K = (f16*)(wa + KOFF);
        int d = (t >= 14) ? (t - 14) : (t + 2);
        float invf = __expf(-(float)(d >> 1) * 1.1512925464970229f); // ln(1e4)/8
        float sgn  = (d & 1) ? 1.f : -1.f;
        float sqd = sq[d], oqd = oq[d], skd = sk[d], okd = ok[d];
        #pragma unroll
        for (int mt = 0; mt < 4; ++mt)
            #pragma unroll
            for (int r = 0; r < 4; ++r) {
                int seq = 16 * mt + 4 * g + r;
                float qv = qkv[mt][r] * sqd + oqd;
                float kv = qkv[mt][r] * skd + okd;
                float qp = __shfl_xor(qv, 1);
                float kp = __shfl_xor(kv, 1);
                float sn, cs;
                __sincosf((float)seq * invf, &sn, &cs);
                Q[seq * 20 + d] = (f16)(qv * cs + sgn * qp * sn);
                K[seq * 20 + d] = (f16)(kv * cs + sgn * kp * sn);
            }
    }

    // ================= phase D: P^T = (K Q^T)/4, masked, softmax =================
    f16x4 ak[4], bq_[4];
    #pragma unroll
    for (int m4 = 0; m4 < 4; ++m4) ak[m4]  = *(f16x4*)(wa + KOFF + (16 * m4 + t) * 40 + 8 * g);
    #pragma unroll
    for (int n4 = 0; n4 < 4; ++n4) bq_[n4] = *(f16x4*)(wa + QOFF + (16 * n4 + t) * 40 + 8 * g);

    f32x4 pT[4][4];
    #pragma unroll
    for (int m4 = 0; m4 < 4; ++m4)
        #pragma unroll
        for (int n4 = 0; n4 < 4; ++n4) {
            f32x4 z; z[0]=0.f; z[1]=0.f; z[2]=0.f; z[3]=0.f;
            pT[m4][n4] = __builtin_amdgcn_mfma_f32_16x16x16f16(ak[m4], bq_[n4], z, 0, 0, 0);
        }

    float mjv[4][4];
    #pragma unroll
    for (int m4 = 0; m4 < 4; ++m4)
        #pragma unroll
        for (int r = 0; r < 4; ++r) mjv[m4][r] = M[16 * m4 + 4 * g + r];

    // Q/K region is dead once pT is computed; P writes below overwrite it.
    // P[i][j]: j=50,51 are natural zeros (masked exp); j>=52 not stored.
    #pragma unroll
    for (int n4 = 0; n4 < 4; ++n4) {
        float a_[4][4]; float mx = -INFINITY;
        #pragma unroll
        for (int m4 = 0; m4 < 4; ++m4)
            #pragma unroll
            for (int r = 0; r < 4; ++r) {
                float mj = mjv[m4][r];
                float av = pT[m4][n4][r] * 0.25f * mj - (1.f - mj) * NEGBIG;
                a_[m4][r] = av; mx = fmaxf(mx, av);
            }
        mx = fmaxf(mx, __shfl_xor(mx, 16)); mx = fmaxf(mx, __shfl_xor(mx, 32));
        float sm = 0.f;
        #pragma unroll
        for (int m4 = 0; m4 < 4; ++m4)
            #pragma unroll
            for (int r = 0; r < 4; ++r) { float e = __expf(a_[m4][r] - mx); a_[m4][r] = e; sm += e; }
        sm += __shfl_xor(sm, 16); sm += __shfl_xor(sm, 32);
        float inv = rcpf(sm);
        int i = t + 16 * n4;
        if (i < SEQ) {
            #pragma unroll
            for (int m4 = 0; m4 < 4; ++m4) {
                if (m4 == 3 && g != 0) continue;          // colb would exceed 104B row
                f16x4 pk;
                #pragma unroll
                for (int r = 0; r < 4; ++r) pk[r] = (f16)(a_[m4][r] * inv);
                *(f16x4*)(wa + i * PSTR + (16 * m4 + 4 * g) * 2) = pk;   // P[i][j]
            }
        }
    }

    // ================= phase F: out = P @ v =================
    // kt=1 fragments: k=32+8g+jj; k>=52 slots are cross-row garbage on BOTH A and B
    // -> zero the B (V) side words so A-garbage multiplies by 0.
    f16x8 bv[3][2];
    #pragma unroll
    for (int nt = 0; nt < 3; ++nt)
        #pragma unroll
        for (int kt = 0; kt < 2; ++kt) {
            f16x8 v = *(f16x8*)(wa + VOFF + (t + 16 * nt) * PSTR + (32 * kt + 8 * g) * 2);
            if (kt == 1) {
                u32x4 w = __builtin_bit_cast(u32x4, v);
                unsigned mlo = (g <= 2) ? 0xFFFFFFFFu : 0u;   // words 0,1: k=32+8g+0..3
                unsigned mhi = (g <= 1) ? 0xFFFFFFFFu : 0u;   // words 2,3: k=32+8g+4..7
                w[0] &= mlo; w[1] &= mlo; w[2] &= mhi; w[3] &= mhi;
                v = __builtin_bit_cast(f16x8, w);
            }
            bv[nt][kt] = v;
        }

    f32x4 oA[4][3];
    #pragma unroll
    for (int mt = 0; mt < 4; ++mt)
        #pragma unroll
        for (int nt = 0; nt < 3; ++nt) { f32x4 z; z[0]=0.f; z[1]=0.f; z[2]=0.f; z[3]=0.f; oA[mt][nt] = z; }

    #pragma unroll
    for (int mt = 0; mt < 4; ++mt) {
        int pr = 16 * mt + t; if (pr > SEQ - 1) pr = SEQ - 1;      // clamp: rows >=50 masked later
        #pragma unroll
        for (int kt = 0; kt < 2; ++kt) {
            f16x8 ap = *(f16x8*)(wa + pr * PSTR + (32 * kt + 8 * g) * 2);
            #pragma unroll
            for (int nt = 0; nt < 3; ++nt)
                oA[mt][nt] = __builtin_amdgcn_mfma_f32_16x16x32_f16(ap, bv[nt][kt], oA[mt][nt], 0, 0, 0);
        }
    }

    // out -> out_lds (reuse P region): out[i = 4g+r+16mt][u = t+16nt], f16
    #pragma unroll
    for (int mt = 0; mt < 4; ++mt)
        #pragma unroll
        for (int nt = 0; nt < 3; ++nt) {
            int u = t + 16 * nt;
            if (u < UNITD) {
                #pragma unroll
                for (int r = 0; r < 4; ++r) {
                    int i = 4 * g + r + 16 * mt;
                    if (i < SEQ)
                        *(f16*)(wa + i * PSTR + u * 2) = (f16)oA[mt][nt][r];
                }
            }
        }

    // ================= phase G: out2^T = Wo @ out^T (+bo) =================
    // stale/garbage bytes at k=u>=46 are annihilated by aw==0 there (prep-built).
    f16x8 aw[3][2];
    #pragma unroll
    for (int mo = 0; mo < 3; ++mo)
        #pragma unroll
        for (int kt = 0; kt < 2; ++kt)
            aw[mo][kt] = wf[512 + (mo * 2 + kt) * 64 + lane];

    f32x4 o2[3][4];
    #pragma unroll
    for (int mo = 0; mo < 3; ++mo)
        #pragma unroll
        for (int n4 = 0; n4 < 4; ++n4) { f32x4 z; z[0]=0.f; z[1]=0.f; z[2]=0.f; z[3]=0.f; o2[mo][n4] = z; }

    #pragma unroll
    for (int n4 = 0; n4 < 4; ++n4) {
        int br = t + 16 * n4; if (br > SEQ - 1) br = SEQ - 1;      // clamp: cols >=50 masked later
        #pragma unroll
        for (int kt = 0; kt < 2; ++kt) {
            f16x8 bo_ = *(f16x8*)(wa + br * PSTR + (32 * kt + 8 * g) * 2);
            #pragma unroll
            for (int mo = 0; mo < 3; ++mo)
                o2[mo][n4] = __builtin_amdgcn_mfma_f32_16x16x32_f16(aw[mo][kt], bo_, o2[mo][n4], 0, 0, 0);
        }
    }

    float bov[3][4], wqv[3][4];
    #pragma unroll
    for (int mo = 0; mo < 3; ++mo)
        #pragma unroll
        for (int r = 0; r < 4; ++r) {
            int o = 16 * mo + 4 * g + r; bool ok2 = (o < UNITD);
            bov[mo][r] = ok2 ? bo[o] : 0.f;
            wqv[mo][r] = ok2 ? Wq[o] : 0.f;
        }
    #pragma unroll
    for (int mo = 0; mo < 3; ++mo)
        #pragma unroll
        for (int n4 = 0; n4 < 4; ++n4)
            #pragma unroll
            for (int r = 0; r < 4; ++r) o2[mo][n4][r] += bov[mo][r];

    // ================= phase H: prob = softmax_i(out2 . Wq + bq, masked) =================
    float bq0 = bq[0];
    float tv[4]; float mx2 = -INFINITY;
    #pragma unroll
    for (int n4 = 0; n4 < 4; ++n4) {
        float s = 0.f;
        #pragma unroll
        for (int mo = 0; mo < 3; ++mo)
            #pragma unroll
            for (int r = 0; r < 4; ++r) s += o2[mo][n4][r] * wqv[mo][r];
        s += __shfl_xor(s, 16); s += __shfl_xor(s, 32);
        float hq = s + bq0;
        float mi = M[t + 16 * n4];
        tv[n4] = hq * mi - (1.f - mi) * NEGBIG;
        mx2 = fmaxf(mx2, tv[n4]);
    }
    #pragma unroll
    for (int off = 1; off <= 8; off <<= 1) mx2 = fmaxf(mx2, __shfl_xor(mx2, off));
    float sm2 = 0.f;
    #pragma unroll
    for (int n4 = 0; n4 < 4; ++n4) { float e = __expf(tv[n4] - mx2); tv[n4] = e; sm2 += e; }
    #pragma unroll
    for (int off = 1; off <= 8; off <<= 1) sm2 += __shfl_xor(sm2, off);
    float inv2 = rcpf(sm2);

    // ================= phase I: result[o] = sum_i out2[i][o] * prob[i] =================
    #pragma unroll
    for (int mo = 0; mo < 3; ++mo) {
        float racc[4];
        #pragma unroll
        for (int r = 0; r < 4; ++r) {
            float a = 0.f;
            #pragma unroll
            for (int n4 = 0; n4 < 4; ++n4) a += o2[mo][n4][r] * tv[n4];
            racc[r] = a;
        }
        #pragma unroll
        for (int off = 1; off <= 8; off <<= 1)
            #pragma unroll
            for (int r = 0; r < 4; ++r) racc[r] += __shfl_xor(racc[r], off);
        if (t == 0) {
            #pragma unroll
            for (int r = 0; r < 4; ++r) {
                int o = 16 * mo + 4 * g + r;
                if (o < UNITD) out[(size_t)b * UNITD + o] = racc[r] * inv2;
            }
        }
    }
}

extern "C" void kernel_launch(void* const* d_in, const int* in_sizes, int n_in,
                              void* d_out, int out_size, void* d_ws, size_t ws_size,
                              hipStream_t stream) {
    const float* x    = (const float*)d_in[0];
    const float* mask = (const float*)d_in[1];
    const float* Wi   = (const float*)d_in[2];
    const float* bi   = (const float*)d_in[3];
    const float* Wo   = (const float*)d_in[4];
    const float* bo   = (const float*)d_in[5];
    const float* sq   = (const float*)d_in[6];
    const float* oq   = (const float*)d_in[7];
    const float* sk   = (const float*)d_in[8];
    const float* ok   = (const float*)d_in[9];
    const float* Wq   = (const float*)d_in[10];
    const float* bq   = (const float*)d_in[11];
    float* outp       = (float*)d_out;

    prep_kernel<<<1, 64, 0, stream>>>(Wi, Wo, (f16x8*)d_ws);

    const int B = in_sizes[0] / (SEQ * UNITD);
    const int blocks = (B + 3) / 4;
    gau_kernel<<<blocks, 256, 0, stream>>>(x, mask, (const f16x8*)d_ws, bi, bo,
                                           sq, oq, sk, ok, Wq, bq, outp, B);
}